// Round 8
// baseline (17658.849 us; speedup 1.0000x reference)
//
#include <hip/hip_runtime.h>
#include <stdint.h>

typedef unsigned short u16;
typedef unsigned int   u32;
typedef unsigned long long u64;
typedef __attribute__((ext_vector_type(4)))  int   i32x4;
typedef __attribute__((ext_vector_type(4)))  float f32x4;
typedef __attribute__((ext_vector_type(8)))  u16   u16x8;
typedef __attribute__((ext_vector_type(8)))  short s16x8;

typedef __attribute__((address_space(3))) char  as3_char;
typedef __attribute__((address_space(3))) i32x4 as3_i32x4;
typedef __attribute__((address_space(3))) s16x8 as3_s16x8;

#define B_    64
#define T_    512
#define DIN_  512
#define H_    1024
#define NBLK_ 128
#define NTHR_ 512

#define HN_BASE_  (64ull*512*1024)
#define CN_BASE_  (HN_BASE_ + 2ull*64*1024)

// ---- workspace layout (bytes) ----
#define WB0_OFF  0ull
#define WB0_SZ   (16ull*8*48*2048)        // [j][wave][jj][2 frag x 1KB] bf16, fragment-major
#define WB1_OFF  (WB0_OFF + WB0_SZ)
#define WB1_SZ   (16ull*8*64*2048)
#define XT_OFF   (WB1_OFF + WB1_SZ)
#define XT_SZ    (512ull*64*512*2)        // [t][b][d] bf16
#define HB_OFF   (XT_OFF + XT_SZ)
#define HBUF_    131072ull                // one [64][1024] bf16 buffer
// h0[2], h1[2]  (parity-indexed double buffers)
#define BIAS_OFF (HB_OFF + 4*HBUF_)
#define SYNC_OFF (BIAS_OFF + 32768)

__device__ __forceinline__ u16 f2bf(float f) {   // RNE fp32 -> bf16
  u32 u = __builtin_bit_cast(u32, f);
  return (u16)((u + 0x7FFFu + ((u >> 16) & 1u)) >> 16);
}
__device__ __forceinline__ float sigf(float x) {
  float e = __builtin_amdgcn_exp2f(x * -1.442695041f);
  return __builtin_amdgcn_rcpf(1.0f + e);
}
__device__ __forceinline__ float tanhf_fast(float x) {
  float e = __builtin_amdgcn_exp2f(x * -2.885390082f);
  float r = __builtin_amdgcn_rcpf(1.0f + e);
  return fmaf(2.0f, r, -1.0f);
}

#define VMW(n)  asm volatile("s_waitcnt vmcnt(" #n ")" ::: "memory")
#define GLOADC(dst, a)  asm volatile("global_load_dwordx4 %0, %1, off sc0 sc1" : "=v"(dst) : "v"(a))

// ============================ prep kernels ============================

__global__ void prep_misc(const float* __restrict__ bih0, const float* __restrict__ bhh0,
                          const float* __restrict__ bih1, const float* __restrict__ bhh1,
                          float* __restrict__ bias, u32* __restrict__ hz,
                          u32* __restrict__ sync)
{
  int i = blockIdx.x * 256 + threadIdx.x;        // 1024*256 = 262144 threads
  if (i < 4096) bias[i] = bih0[i] + bhh0[i];
  else if (i < 8192) bias[i] = bih1[i - 4096] + bhh1[i - 4096];
  if (i < 131072) hz[i] = 0u;                    // zero h0[2], h1[2] (512 KB)
  if (i < 256) sync[i] = 0u;
}

// W[k][n] fp32 -> fragment-major bf16:
//   j = hcol>>6 (16 col-blocks of 256 gate-cols); within block, col
//   cc = grp_local*64 + gate*16 + h15 (grp_local=(hcol>>4)&3, h15=hcol&15);
//   wave w = cc>>5, frag f = (cc>>4)&1, l15 = cc&15; k -> jj = k>>5, lg = (k>>3)&3.
//   dest byte = j*(8*NS*2048) + ((w*NS+jj)*2+f)*1024 + (lg*16+l15)*16
//   -> each wave's per-jj fragment is one CONTIGUOUS 1KB (lane*16), streamed
//      sequentially over jj (fixes 4KB-stride L1 set-thrashing of rounds 5-7).
__global__ void prep_w(const float* __restrict__ Wih0, const float* __restrict__ Whh0,
                       const float* __restrict__ Wih1, const float* __restrict__ Whh1,
                       u16* __restrict__ Wb0, u16* __restrict__ Wb1)
{
  __shared__ u16 tile[64][72];
  const int bid = blockIdx.x;
  const int layer = (bid >= 1536) ? 1 : 0;
  const int lb = layer ? bid - 1536 : bid;
  const int nkt = layer ? 32 : 24;
  const int kt = lb % nkt, nt = lb / nkt;
  const int K = layer ? 2048 : 1536;
  const int NS = K >> 5;
  const int xlen = layer ? 1024 : 512;
  const float* Wih = layer ? Wih1 : Wih0;
  const float* Whh = layer ? Whh1 : Whh0;
  char* Wb = (char*)(layer ? Wb1 : Wb0);
  const int k0 = kt * 64, n0 = nt * 64;
  const int t = threadIdx.x;
  {
    int kr = t >> 2, ncs = (t & 3) * 16;
    int kk = k0 + kr;
    const float* src = (kk < xlen) ? (Wih + (size_t)kk * 4096)
                                   : (Whh + (size_t)(kk - xlen) * 4096);
    const float* p = src + n0 + ncs;
#pragma unroll
    for (int v = 0; v < 4; ++v) {
      f32x4 f = *(const f32x4*)(p + v * 4);
#pragma unroll
      for (int e = 0; e < 4; ++e) tile[kr][ncs + v*4 + e] = f2bf(f[e]);
    }
  }
  __syncthreads();
  {
    int c2 = t >> 2;
    int n = n0 + c2;
    int gate = n >> 10, hcol = n & 1023;
    int jblk = hcol >> 6;
    int grpl = (hcol >> 4) & 3, h15 = hcol & 15;
    int cc = grpl * 64 + gate * 16 + h15;
    int w = cc >> 5, f = (cc >> 4) & 1, l15 = cc & 15;
    char* blkbase = Wb + (size_t)jblk * ((size_t)8 * NS * 2048);
#pragma unroll
    for (int kv = 0; kv < 2; ++kv) {
      int k8 = (t & 3) + 4 * kv;
      int jj = (k0 >> 5) + (k8 >> 2);
      int lg = k8 & 3;
      size_t off = (size_t)((w * NS + jj) * 2 + f) * 1024 + (size_t)(lg * 16 + l15) * 16;
      u16x8 vv;
#pragma unroll
      for (int e = 0; e < 8; ++e) vv[e] = tile[k8*8 + e][c2];
      *(u16x8*)(blkbase + off) = vv;
    }
  }
}

// x [b][t][d] fp32 -> xT [t][b][d] bf16
__global__ void prep_x(const float* __restrict__ x, u16* __restrict__ xT)
{
  int i = blockIdx.x * 256 + threadIdx.x;
  int d16 = (i & 31) << 4;
  int b   = (i >> 5) & 63;
  int tt  = i >> 11;
  const float* s = x + ((size_t)b * T_ + tt) * DIN_ + d16;
  u16* d = xT + ((size_t)tt * B_ + b) * DIN_ + d16;
  f32x4 fa = *(const f32x4*)(s);
  f32x4 fb = *(const f32x4*)(s + 4);
  f32x4 fc = *(const f32x4*)(s + 8);
  f32x4 fd = *(const f32x4*)(s + 12);
  u16x8 o0, o1;
#pragma unroll
  for (int e = 0; e < 4; ++e) {
    o0[e] = f2bf(fa[e]); o0[4+e] = f2bf(fb[e]);
    o1[e] = f2bf(fc[e]); o1[4+e] = f2bf(fd[e]);
  }
  *(u16x8*)d = o0;
  *(u16x8*)(d + 8) = o1;
}

// ============================ persistent LSTM kernel ============================
// 128 blocks x 512 threads. bid = layer*64 + i*16 + j (geometry identical to the
// PASSING round 7: i = 16-row group, j = 16 col-groups of 256 gate-cols, XCD=j%8,
// coherent h-broadcast 6 MB/step). ONLY change vs round 7: B is read from the
// fragment-major layout -- per wave a contiguous 96/128 KB stream (2KB/jj-pair),
// eliminating the 4KB-stride L1 set-thrash that made the B stream ~40 GB/s/CU.

template<int LAYER>
__device__ __forceinline__ void phase(
    const int t, const int i16, const int tid,
    const u16* __restrict__ xt, const char* __restrict__ wb,
    const char* __restrict__ srcH0, const char* __restrict__ srcH1,
    u16* __restrict__ wr,
    const float b0, const float b1, const float b2, const float b3,
    const int colg, float (&cst)[2],
    float* __restrict__ out, as3_char* ldsA, float* gatesL)
{
  constexpr int K   = LAYER ? 2048 : 1536;
  constexpr int RS  = K * 2 + 32;        // padded LDS row stride (bytes)
  constexpr int NS  = K / 32;            // k32 slices
  constexpr int CH  = LAYER ? 8 : 6;     // 16B chunks per thread (A staging, 16 rows)
  constexpr int CPR = K / 8;             // 16B chunks per A row
  const int lane = tid & 63, w = tid >> 6;
  const int l15 = lane & 15, lg = lane >> 4;

  // ---- stage A [16 rows x K]: issue ALL loads, vmcnt(0), LDS write ----
  i32x4 st[8]; int dsd[8];
#pragma unroll
  for (int c = 0; c < CH; ++c) {
    int ch = c * 512 + tid;
    int row = ch / CPR, k16 = ch - row * CPR;
    if (LAYER == 0) {
      if (k16 < 64) {
        st[c] = *(const i32x4*)((const char*)xt + ((size_t)(i16 + row) * 512 + k16 * 8) * 2);
      } else {
        u64 a = (u64)(srcH0 + ((size_t)(i16 + row) * 1024 + (k16 - 64) * 8) * 2);
        GLOADC(st[c], a);
      }
    } else {
      const char* bs = (k16 < 128) ? srcH0 : srcH1;
      int kk = (k16 < 128) ? k16 : k16 - 128;
      u64 a = (u64)(bs + ((size_t)(i16 + row) * 1024 + kk * 8) * 2);
      GLOADC(st[c], a);
    }
    dsd[c] = row * RS + k16 * 16;
  }
  VMW(0);
  __builtin_amdgcn_sched_barrier(0);
#pragma unroll
  for (int c = 0; c < CH; ++c) *(as3_i32x4*)(ldsA + dsd[c]) = st[c];
  __syncthreads();

  // ---- GEMM: wave w -> cols w*32..+32; B = contiguous fragment stream ----
  f32x4 ac00 = {}, ac01 = {}, ac10 = {}, ac11 = {};
  const as3_char* arow = ldsA + (size_t)l15 * RS;
  const char* bbase = wb + (size_t)w * (NS * 2048) + (size_t)lane * 16;
#pragma unroll
  for (int jj = 0; jj < NS; jj += 2) {
    s16x8 a0  = *(const as3_s16x8*)(arow + jj * 64 + lg * 16);
    s16x8 a1  = *(const as3_s16x8*)(arow + (jj + 1) * 64 + lg * 16);
    s16x8 b00 = *(const s16x8*)(bbase + (size_t)jj * 2048);
    s16x8 b10 = *(const s16x8*)(bbase + (size_t)jj * 2048 + 1024);
    s16x8 b01 = *(const s16x8*)(bbase + (size_t)(jj + 1) * 2048);
    s16x8 b11 = *(const s16x8*)(bbase + (size_t)(jj + 1) * 2048 + 1024);
    ac00 = __builtin_amdgcn_mfma_f32_16x16x32_bf16(a0, b00, ac00, 0, 0, 0);
    ac01 = __builtin_amdgcn_mfma_f32_16x16x32_bf16(a1, b01, ac01, 0, 0, 0);
    ac10 = __builtin_amdgcn_mfma_f32_16x16x32_bf16(a0, b10, ac10, 0, 0, 0);
    ac11 = __builtin_amdgcn_mfma_f32_16x16x32_bf16(a1, b11, ac11, 0, 0, 0);
  }
  f32x4 acc0 = ac00 + ac01;
  f32x4 acc1 = ac10 + ac11;

  // ---- gates exchange: gatesL[cc(256)][row(16+4 pad)] fp32 ----
  *(f32x4*)(gatesL + (size_t)(w * 32 + l15) * 20 + lg * 4)      = acc0;
  *(f32x4*)(gatesL + (size_t)(w * 32 + 16 + l15) * 20 + lg * 4) = acc1;
  __syncthreads();

  // ---- cell update: thread = (hc=tid&63, rows tid>>6 and +8) ----
  {
    const int hc = tid & 63, rw = tid >> 6;
    const int ccb = (hc >> 4) * 64 + (hc & 15);   // cc = grp_local*64 + gate*16 + h15
#pragma unroll
    for (int e = 0; e < 2; ++e) {
      int row = rw + 8 * e;
      float g0 = gatesL[(size_t)(ccb + 0 * 16) * 20 + row];
      float g1 = gatesL[(size_t)(ccb + 1 * 16) * 20 + row];
      float g2 = gatesL[(size_t)(ccb + 2 * 16) * 20 + row];
      float g3 = gatesL[(size_t)(ccb + 3 * 16) * 20 + row];
      float ig = sigf(g0 + b0);
      float fg = sigf(g1 + b1);
      float cg = fmaxf(g2 + b2, 0.0f);
      float og = sigf(g3 + b3);
      float cn = fg * cst[e] + ig * cg;
      cst[e] = cn;
      float h = og * tanhf_fast(cn);
      u32 hb = (u32)f2bf(h);
      int rowg = i16 + row;
      u64 a0 = (u64)((char*)wr + ((size_t)rowg * 1024 + colg) * 2);
      asm volatile("global_store_short %0, %1, off sc0 sc1" :: "v"(a0), "v"(hb) : "memory");
      if (LAYER == 1) out[((size_t)rowg * T_ + t) * H_ + colg] = h;
      if (t == T_ - 1) {
        out[HN_BASE_ + ((size_t)LAYER * 64 + rowg) * H_ + colg] = h;
        out[CN_BASE_ + ((size_t)LAYER * 64 + rowg) * H_ + colg] = cn;
      }
    }
  }
}

__global__ __launch_bounds__(NTHR_, 1) void lstm_persist(
    const u16* __restrict__ xT, const u16* __restrict__ Wb0, const u16* __restrict__ Wb1,
    char* __restrict__ hb, const float* __restrict__ bias,
    u32* __restrict__ sync, float* __restrict__ out)
{
  __shared__ __align__(16) char ldsAraw[16 * (2048 * 2 + 32)];   // 66 KB (max layer)
  __shared__ __align__(16) float gatesL[256 * 20];               // 20 KB
  as3_char* ldsA = (as3_char*)ldsAraw;
  const int tid = threadIdx.x;
  const int bid = blockIdx.x;
  const int layer = bid >> 6, i = (bid >> 4) & 3, j = bid & 15;
  const int i16 = i * 16;
  const char* wb = layer ? ((const char*)Wb1 + (size_t)j * (8ull * 64 * 2048))
                         : ((const char*)Wb0 + (size_t)j * (8ull * 48 * 2048));
  char* h0 = hb;                        // [par][64][1024] bf16
  char* h1 = hb + 2 * HBUF_;
  const int hc = tid & 63;
  const int colg = j * 64 + hc;
  float b0, b1, b2, b3;
  {
    const float* bb = bias + layer * 4096;
    b0 = bb[colg]; b1 = bb[1024 + colg]; b2 = bb[2048 + colg]; b3 = bb[3072 + colg];
  }
  float cst[2] = {0.f, 0.f};

  for (int s = 0; s <= T_; ++s) {
    const size_t rp = (size_t)((s + 1) & 1) * HBUF_;
    const size_t wp = (size_t)(s & 1) * HBUF_;
    if (layer == 0) {
      if (s < T_)
        phase<0>(s, i16, tid, xT + (size_t)s * B_ * DIN_, wb,
                 h0 + rp, nullptr, (u16*)(h0 + wp),
                 b0, b1, b2, b3, colg, cst, out, ldsA, gatesL);
    } else {
      if (s >= 1)
        phase<1>(s - 1, i16, tid, nullptr, wb,
                 h0 + rp, h1 + rp, (u16*)(h1 + wp),
                 b0, b1, b2, b3, colg, cst, out, ldsA, gatesL);
    }
    // ---- tree grid barrier: 8 leaves x 16 -> root -> broadcast flag ----
    VMW(0);
    __syncthreads();
    if (tid == 0) {
      u32* leaf = sync + (bid >> 4) * 16;
      u32 old = __hip_atomic_fetch_add(leaf, 1u, __ATOMIC_RELAXED, __HIP_MEMORY_SCOPE_AGENT);
      if (old == (u32)s * 16u + 15u) {
        u32 r = __hip_atomic_fetch_add(sync + 128, 1u, __ATOMIC_RELAXED, __HIP_MEMORY_SCOPE_AGENT);
        if (r == (u32)s * 8u + 7u)
          __hip_atomic_store(sync + 144, (u32)(s + 1), __ATOMIC_RELAXED, __HIP_MEMORY_SCOPE_AGENT);
      }
      while (__hip_atomic_load(sync + 144, __ATOMIC_RELAXED, __HIP_MEMORY_SCOPE_AGENT) < (u32)(s + 1))
        __builtin_amdgcn_s_sleep(2);
    }
    __syncthreads();
  }
}

// ============================ host launch ============================

extern "C" void kernel_launch(void* const* d_in, const int* in_sizes, int n_in,
                              void* d_out, int out_size, void* d_ws, size_t ws_size,
                              hipStream_t stream)
{
  const float* x    = (const float*)d_in[0];
  const float* Wih0 = (const float*)d_in[1];
  const float* bih0 = (const float*)d_in[2];
  const float* Whh0 = (const float*)d_in[3];
  const float* bhh0 = (const float*)d_in[4];
  const float* Wih1 = (const float*)d_in[5];
  const float* bih1 = (const float*)d_in[6];
  const float* Whh1 = (const float*)d_in[7];
  const float* bhh1 = (const float*)d_in[8];

  char* ws = (char*)d_ws;
  u16* Wb0    = (u16*)(ws + WB0_OFF);
  u16* Wb1    = (u16*)(ws + WB1_OFF);
  u16* xT     = (u16*)(ws + XT_OFF);
  char* hb    = ws + HB_OFF;
  float* bias = (float*)(ws + BIAS_OFF);
  u32* sync   = (u32*)(ws + SYNC_OFF);
  float* out  = (float*)d_out;

  prep_misc<<<1024, 256, 0, stream>>>(bih0, bhh0, bih1, bhh1, bias, (u32*)hb, sync);
  prep_w<<<3584, 256, 0, stream>>>(Wih0, Whh0, Wih1, Whh1, Wb0, Wb1);
  prep_x<<<4096, 256, 0, stream>>>(x, xT);
  lstm_persist<<<NBLK_, NTHR_, 0, stream>>>(xT, Wb0, Wb1, hb, bias, sync, out);
}

// Round 9
// 12806.271 us; speedup vs baseline: 1.3789x; 1.3789x over previous
//
#include <hip/hip_runtime.h>
#include <stdint.h>

typedef unsigned short u16;
typedef unsigned int   u32;
typedef unsigned long long u64;
typedef __attribute__((ext_vector_type(4)))  int   i32x4;
typedef __attribute__((ext_vector_type(4)))  float f32x4;
typedef __attribute__((ext_vector_type(8)))  u16   u16x8;
typedef __attribute__((ext_vector_type(8)))  short s16x8;

typedef __attribute__((address_space(3))) char  as3_char;
typedef __attribute__((address_space(3))) i32x4 as3_i32x4;
typedef __attribute__((address_space(3))) s16x8 as3_s16x8;

#define B_    64
#define T_    512
#define DIN_  512
#define H_    1024
#define NBLK_ 256
#define NTHR_ 512

#define HN_BASE_  (64ull*512*1024)
#define CN_BASE_  (HN_BASE_ + 2ull*64*1024)

// ---- workspace layout (bytes) ----
// Weights fragment-major PER 32-COL BLOCK (j=0..127): slice = 2 n-tiles x NS x 1KB.
#define WB0_OFF  0ull
#define WB0_SZ   (128ull*48*2048)         // 12.6 MB (NS=48)
#define WB1_OFF  (WB0_OFF + WB0_SZ)
#define WB1_SZ   (128ull*64*2048)         // 16.8 MB (NS=64)
#define RING_OFF (WB1_OFF + WB1_SZ)
#define RSLOT_   131072ull                // one [64][1024] bf16 h0 snapshot
#define RING_SZ  (513ull*RSLOT_)          // 67.2 MB: slot t+1 = h0[t]; slot 0 = zeros
#define BIAS_OFF (RING_OFF + RING_SZ)
#define SYNC_OFF (BIAS_OFF + 32768)

__device__ __forceinline__ u16 f2bf(float f) {   // RNE fp32 -> bf16
  u32 u = __builtin_bit_cast(u32, f);
  return (u16)((u + 0x7FFFu + ((u >> 16) & 1u)) >> 16);
}
__device__ __forceinline__ float sigf(float x) {
  float e = __builtin_amdgcn_exp2f(x * -1.442695041f);
  return __builtin_amdgcn_rcpf(1.0f + e);
}
__device__ __forceinline__ float tanhf_fast(float x) {
  float e = __builtin_amdgcn_exp2f(x * -2.885390082f);
  float r = __builtin_amdgcn_rcpf(1.0f + e);
  return fmaf(2.0f, r, -1.0f);
}

#define VMW(n)  asm volatile("s_waitcnt vmcnt(" #n ")" ::: "memory")

// ============================ prep kernels ============================

__global__ void prep_misc(const float* __restrict__ bih0, const float* __restrict__ bhh0,
                          const float* __restrict__ bih1, const float* __restrict__ bhh1,
                          float* __restrict__ bias, u32* __restrict__ ring0,
                          u32* __restrict__ sync)
{
  int i = blockIdx.x * 256 + threadIdx.x;
  if (i < 4096) bias[i] = bih0[i] + bhh0[i];
  else if (i < 8192) bias[i] = bih1[i - 4096] + bhh1[i - 4096];
  if (i < 32768) ring0[i] = 0u;                  // zero ring slot 0 (h0[-1] = 0)
  if (i < 256) sync[i] = 0u;
}

// W[k][n] fp32 -> fragment-major bf16 per 32-col block:
//   gate = n>>10, hcol = n&1023, j = hcol>>3, hl = hcol&7, cc = hl*4+gate,
//   nt = cc>>4, l15 = cc&15; k: jj = k>>5, lg = (k>>3)&3, e = k&7.
//   dest = Wb + j*(NS*2048) + (nt*NS+jj)*1024 + (lg*16+l15)*16 + e*2.
//   (fragment convention identical to round-8's, which passed validation)
__global__ void prep_w(const float* __restrict__ Wih0, const float* __restrict__ Whh0,
                       const float* __restrict__ Wih1, const float* __restrict__ Whh1,
                       u16* __restrict__ Wb0, u16* __restrict__ Wb1)
{
  __shared__ u16 tile[64][72];
  const int bid = blockIdx.x;
  const int layer = (bid >= 1536) ? 1 : 0;
  const int lb = layer ? bid - 1536 : bid;
  const int nkt = layer ? 32 : 24;
  const int kt = lb % nkt, nt_ = lb / nkt;
  const int K = layer ? 2048 : 1536;
  const int NS = K >> 5;
  const int xlen = layer ? 1024 : 512;
  const float* Wih = layer ? Wih1 : Wih0;
  const float* Whh = layer ? Whh1 : Whh0;
  char* Wb = (char*)(layer ? Wb1 : Wb0);
  const int k0 = kt * 64, n0 = nt_ * 64;
  const int t = threadIdx.x;
  {
    int kr = t >> 2, ncs = (t & 3) * 16;
    int kk = k0 + kr;
    const float* src = (kk < xlen) ? (Wih + (size_t)kk * 4096)
                                   : (Whh + (size_t)(kk - xlen) * 4096);
    const float* p = src + n0 + ncs;
#pragma unroll
    for (int v = 0; v < 4; ++v) {
      f32x4 f = *(const f32x4*)(p + v * 4);
#pragma unroll
      for (int e = 0; e < 4; ++e) tile[kr][ncs + v*4 + e] = f2bf(f[e]);
    }
  }
  __syncthreads();
  {
    int c2 = t >> 2;
    int n = n0 + c2;
    int gate = n >> 10, hcol = n & 1023;
    int j = hcol >> 3, hl = hcol & 7;
    int cc = hl * 4 + gate;
    int ntile = cc >> 4, l15 = cc & 15;
    char* base = Wb + (size_t)j * ((size_t)NS * 2048);
#pragma unroll
    for (int kv = 0; kv < 2; ++kv) {
      int k8 = (t & 3) + 4 * kv;
      int jj = (k0 >> 5) + (k8 >> 2);
      int lg = k8 & 3;
      size_t off = (size_t)(ntile * NS + jj) * 1024 + (size_t)(lg * 16 + l15) * 16;
      u16x8 vv;
#pragma unroll
      for (int e = 0; e < 8; ++e) vv[e] = tile[k8*8 + e][c2];
      *(u16x8*)(base + off) = vv;
    }
  }
}

// ============================ persistent LSTM kernel ============================
// 256 blocks x 512 threads (1/CU). bid = layer*128 + j (j = 8 h-cols = 32 gate-cols).
// WEIGHTS IN LDS for the whole kernel (96/128 KB slice, loaded once) -> zero
// per-step weight traffic. Block computes gates [64 x 32] full K.
// A-operand: x read fp32 from d_in (cvt inline); h0 via 513-slot ring (bf16,
// written sc0sc1, read PLAIN-cached -- fresh address per step, L2-dedup per XCD);
// h1 read fp32 from `out` (written sc0sc1). 8 waves = 4 m x 2 n, one 16x16
// C-tile each, pure intrinsic MFMA, B via ds_read from LDS.
// Tree grid barrier 8x32 (round-6 proven).

template<int LAYER>
__device__ __forceinline__ void phase(
    const int t, const int tid, const int j,
    const float* __restrict__ x, const char* __restrict__ ring,
    float* __restrict__ out,
    const float b0, const float b1, const float b2, const float b3,
    const int colg, float& cst, as3_char* wLds, float* gatesL)
{
  constexpr int K  = LAYER ? 2048 : 1536;
  constexpr int NS = K / 32;
  const int lane = tid & 63, w = tid >> 6;
  const int m = w >> 1, ntile = w & 1;
  const int l15 = lane & 15, lg = lane >> 4;
  const int arow = m * 16 + l15;            // batch row this lane's A-frags cover
  const as3_char* bbase = wLds + (size_t)(ntile * NS) * 1024 + (size_t)lane * 16;

  f32x4 ac0 = {}, ac1 = {};
  const u16* h0r = (const u16*)(ring + (size_t)t * RSLOT_);          // h0[t-1]
  const u16* h0n = (const u16*)(ring + (size_t)(t + 1) * RSLOT_);    // h0[t] (layer1)

#pragma unroll
  for (int jj = 0; jj < NS; ++jj) {
    s16x8 af;
    if (LAYER == 0) {
      if (jj < 16) {                        // x part: fp32 -> bf16 inline
        const float* xp = x + ((size_t)arow * T_ + t) * DIN_ + jj * 32 + lg * 8;
        f32x4 u = *(const f32x4*)xp;
        f32x4 v = *(const f32x4*)(xp + 4);
        u16x8 p;
#pragma unroll
        for (int e = 0; e < 4; ++e) { p[e] = f2bf(u[e]); p[4+e] = f2bf(v[e]); }
        af = __builtin_bit_cast(s16x8, p);
      } else {                              // h0[t-1] part (plain cached)
        af = *(const s16x8*)(h0r + (size_t)arow * H_ + (jj - 16) * 32 + lg * 8);
      }
    } else {
      if (jj < 32) {                        // h0[t] part
        af = *(const s16x8*)(h0n + (size_t)arow * H_ + jj * 32 + lg * 8);
      } else {                              // h1[t-1] from out (fp32)
        if (t >= 1) {
          const float* op = out + ((size_t)arow * T_ + (t - 1)) * H_ + (jj - 32) * 32 + lg * 8;
          f32x4 u = *(const f32x4*)op;
          f32x4 v = *(const f32x4*)(op + 4);
          u16x8 p;
#pragma unroll
          for (int e = 0; e < 4; ++e) { p[e] = f2bf(u[e]); p[4+e] = f2bf(v[e]); }
          af = __builtin_bit_cast(s16x8, p);
        } else {
          af = s16x8{0,0,0,0,0,0,0,0};
        }
      }
    }
    s16x8 bv = *(const as3_s16x8*)(bbase + (size_t)jj * 1024);
    if (jj & 1) ac1 = __builtin_amdgcn_mfma_f32_16x16x32_bf16(af, bv, ac1, 0, 0, 0);
    else        ac0 = __builtin_amdgcn_mfma_f32_16x16x32_bf16(af, bv, ac0, 0, 0, 0);
  }
  f32x4 acc = ac0 + ac1;

  // ---- gates exchange: gatesL[cc(32)][row(64+4 pad)] ----
  *(f32x4*)(gatesL + (size_t)(ntile * 16 + l15) * 68 + m * 16 + lg * 4) = acc;
  __syncthreads();

  // ---- cell update: thread = (erow = tid>>3, ehl = tid&7) ----
  {
    const int erow = tid >> 3, ehl = tid & 7;
    float g0 = gatesL[(size_t)(ehl * 4 + 0) * 68 + erow];
    float g1 = gatesL[(size_t)(ehl * 4 + 1) * 68 + erow];
    float g2 = gatesL[(size_t)(ehl * 4 + 2) * 68 + erow];
    float g3 = gatesL[(size_t)(ehl * 4 + 3) * 68 + erow];
    float ig = sigf(g0 + b0);
    float fg = sigf(g1 + b1);
    float cg = fmaxf(g2 + b2, 0.0f);
    float og = sigf(g3 + b3);
    float cn = fg * cst + ig * cg;
    cst = cn;
    float h = og * tanhf_fast(cn);
    if (LAYER == 0) {                       // write h0[t] -> ring slot t+1 (sc0sc1)
      u32 hb = (u32)f2bf(h);
      u64 a = (u64)(ring + (size_t)(t + 1) * RSLOT_ + ((size_t)erow * H_ + colg) * 2);
      asm volatile("global_store_short %0, %1, off sc0 sc1" :: "v"(a), "v"(hb) : "memory");
    } else {                                // write out[b][t][h] fp32 (sc0sc1: read cross-XCD)
      u64 a = (u64)((char*)out + (((size_t)erow * T_ + t) * H_ + colg) * 4);
      asm volatile("global_store_dword %0, %1, off sc0 sc1" :: "v"(a), "v"(h) : "memory");
    }
    if (t == T_ - 1) {
      out[HN_BASE_ + ((size_t)LAYER * 64 + erow) * H_ + colg] = h;
      out[CN_BASE_ + ((size_t)LAYER * 64 + erow) * H_ + colg] = cn;
    }
  }
}

__global__ __launch_bounds__(NTHR_, 1) void lstm_persist(
    const float* __restrict__ x, const u16* __restrict__ Wb0, const u16* __restrict__ Wb1,
    char* __restrict__ ring, const float* __restrict__ bias,
    u32* __restrict__ sync, float* __restrict__ out)
{
  __shared__ __align__(16) char wLdsRaw[131072];       // weights slice (96/128 KB)
  __shared__ __align__(16) float gatesL[32 * 68];      // 8.7 KB
  as3_char* wLds = (as3_char*)wLdsRaw;
  const int tid = threadIdx.x;
  const int bid = blockIdx.x;
  const int layer = bid >> 7, j = bid & 127;
  const int NSl = layer ? 64 : 48;
  const char* wbg = layer ? ((const char*)Wb1 + (size_t)j * ((size_t)64 * 2048))
                          : ((const char*)Wb0 + (size_t)j * ((size_t)48 * 2048));

  // ---- one-time: load weight slice into LDS ----
  for (int off = tid * 16; off < NSl * 2048; off += NTHR_ * 16)
    *(as3_i32x4*)(wLds + off) = *(const i32x4*)(wbg + off);
  __syncthreads();

  const int ehl = tid & 7;
  const int colg = j * 8 + ehl;
  float b0, b1, b2, b3;
  {
    const float* bb = bias + layer * 4096;
    b0 = bb[colg]; b1 = bb[1024 + colg]; b2 = bb[2048 + colg]; b3 = bb[3072 + colg];
  }
  float cst = 0.f;

  for (int s = 0; s <= T_; ++s) {
    if (layer == 0) {
      if (s < T_)
        phase<0>(s, tid, j, x, ring, out, b0, b1, b2, b3, colg, cst, wLds, gatesL);
    } else {
      if (s >= 1)
        phase<1>(s - 1, tid, j, x, ring, out, b0, b1, b2, b3, colg, cst, wLds, gatesL);
    }
    // ---- tree grid barrier: 8 leaves x 32 -> root -> broadcast flag ----
    VMW(0);
    __syncthreads();
    if (tid == 0) {
      u32* leaf = sync + (bid >> 5) * 16;
      u32 old = __hip_atomic_fetch_add(leaf, 1u, __ATOMIC_RELAXED, __HIP_MEMORY_SCOPE_AGENT);
      if (old == (u32)s * 32u + 31u) {
        u32 r = __hip_atomic_fetch_add(sync + 128, 1u, __ATOMIC_RELAXED, __HIP_MEMORY_SCOPE_AGENT);
        if (r == (u32)s * 8u + 7u)
          __hip_atomic_store(sync + 144, (u32)(s + 1), __ATOMIC_RELAXED, __HIP_MEMORY_SCOPE_AGENT);
      }
      while (__hip_atomic_load(sync + 144, __ATOMIC_RELAXED, __HIP_MEMORY_SCOPE_AGENT) < (u32)(s + 1))
        __builtin_amdgcn_s_sleep(2);
    }
    __syncthreads();
  }
}

// ============================ host launch ============================

extern "C" void kernel_launch(void* const* d_in, const int* in_sizes, int n_in,
                              void* d_out, int out_size, void* d_ws, size_t ws_size,
                              hipStream_t stream)
{
  const float* x    = (const float*)d_in[0];
  const float* Wih0 = (const float*)d_in[1];
  const float* bih0 = (const float*)d_in[2];
  const float* Whh0 = (const float*)d_in[3];
  const float* bhh0 = (const float*)d_in[4];
  const float* Wih1 = (const float*)d_in[5];
  const float* bih1 = (const float*)d_in[6];
  const float* Whh1 = (const float*)d_in[7];
  const float* bhh1 = (const float*)d_in[8];

  char* ws = (char*)d_ws;
  u16* Wb0    = (u16*)(ws + WB0_OFF);
  u16* Wb1    = (u16*)(ws + WB1_OFF);
  char* ring  = ws + RING_OFF;
  float* bias = (float*)(ws + BIAS_OFF);
  u32* sync   = (u32*)(ws + SYNC_OFF);
  float* out  = (float*)d_out;

  prep_misc<<<1024, 256, 0, stream>>>(bih0, bhh0, bih1, bhh1, bias, (u32*)ring, sync);
  prep_w<<<3584, 256, 0, stream>>>(Wih0, Whh0, Wih1, Whh1, Wb0, Wb1);
  lstm_persist<<<NBLK_, NTHR_, 0, stream>>>(x, Wb0, Wb1, ring, bias, sync, out);
}